// Round 1
// baseline (4031.908 us; speedup 1.0000x reference)
//
#include <hip/hip_runtime.h>
#include <hip/hip_bf16.h>
#include <math.h>

#define Bsz 256
#define Lsz 16
#define Usz 512
#define Dsz 2
#define BPW 2               // batch elements per workgroup
#define NWG (Bsz / BPW)     // 128 workgroups
#define NT  512             // threads per workgroup (8 waves)

// Each workgroup owns BPW batch elements end-to-end: all 256 sequential
// cell updates happen inside the workgroup (no inter-wg sync needed).
// Main matvec: threads = 128 u-quads x 4 k-slices; weights read as float4
// (coalesced, [k][u] layout); h and states read as wave-uniform LDS
// broadcasts; partial sums reduced through LDS each step.
__global__ __launch_bounds__(NT) void rnn2d_baseline(
    const int*   __restrict__ x,     // (B,L,L)
    const float* __restrict__ Wih,   // (D,U)
    const float* __restrict__ Wiv,   // (D,U)
    const float* __restrict__ Wch,   // (U,U)
    const float* __restrict__ bch,   // (U)
    const float* __restrict__ Wcv,   // (U,U)
    const float* __restrict__ Wout,  // (U,D)
    const float* __restrict__ bout,  // (D)
    float*       __restrict__ out)   // (B)
{
    __shared__ float           h[BPW][Usz];            // 4 KB
    __shared__ __hip_bfloat16  st[BPW][Lsz][Usz];      // 32 KB (prev-row states)
    __shared__ float           part[4][BPW][Usz];      // 16 KB
    __shared__ float           wred[NT / 64][BPW][2];  // per-wave logit partials
    __shared__ float           logp[BPW];

    const int tid = threadIdx.x;
    const int b0  = blockIdx.x * BPW;

    // ---- init ----
    if (tid < BPW) logp[tid] = 0.f;
    for (int idx = tid; idx < BPW * Lsz * Usz; idx += NT)
        ((unsigned short*)st)[idx] = 0;   // bf16 zero

    // per-thread cached row of small weights (u == tid, Usz == NT)
    const int   u    = tid;
    const float wih0 = Wih[u],           wih1 = Wih[Usz + u];
    const float wiv0 = Wiv[u],           wiv1 = Wiv[Usz + u];
    const float bc   = bch[u];
    const float wo0  = Wout[u * Dsz + 0], wo1 = Wout[u * Dsz + 1];
    const float bo0  = bout[0],           bo1 = bout[1];

    const int q  = tid & 127;   // u-quad index
    const int s  = tid >> 7;    // k-slice index (0..3)
    const int u0 = q * 4;
    const int k0 = s * 128;

    for (int i = 0; i < Lsz; ++i) {
        const int dir = (i & 1) ? -1 : 1;

        // reset running hidden at row start
        h[0][tid] = 0.f;
        h[1][tid] = 0.f;
        __syncthreads();

        for (int t = 0; t < Lsz; ++t) {
            const int c = (dir == 1) ? t : (Lsz - 1 - t);

            // ---- phase 1: partial matvec over this thread's k-slice ----
            float a00 = 0.f, a01 = 0.f, a02 = 0.f, a03 = 0.f;
            float a10 = 0.f, a11 = 0.f, a12 = 0.f, a13 = 0.f;
            const float* __restrict__ wchp = Wch + (size_t)k0 * Usz + u0;
            const float* __restrict__ wcvp = Wcv + (size_t)k0 * Usz + u0;
            #pragma unroll 4
            for (int k = k0; k < k0 + 128; ++k) {
                const float4 wh = *(const float4*)wchp;  wchp += Usz;
                const float4 wv = *(const float4*)wcvp;  wcvp += Usz;
                const float h0 = h[0][k];
                const float h1 = h[1][k];
                const float v0 = __bfloat162float(st[0][c][k]);
                const float v1 = __bfloat162float(st[1][c][k]);
                a00 += h0 * wh.x + v0 * wv.x;
                a01 += h0 * wh.y + v0 * wv.y;
                a02 += h0 * wh.z + v0 * wv.z;
                a03 += h0 * wh.w + v0 * wv.w;
                a10 += h1 * wh.x + v1 * wv.x;
                a11 += h1 * wh.y + v1 * wv.y;
                a12 += h1 * wh.z + v1 * wv.z;
                a13 += h1 * wh.w + v1 * wv.w;
            }
            *(float4*)&part[s][0][u0] = make_float4(a00, a01, a02, a03);
            *(float4*)&part[s][1][u0] = make_float4(a10, a11, a12, a13);
            __syncthreads();   // [A]

            // ---- phase 3: combine partials, elu, write state, logit partials ----
            const int  cl   = c - dir;      // neighbor in scan order
            const bool hasL = (t > 0);
            const bool hasV = (i > 0);

            float l00, l01, l10, l11;
            {
                // b = 0
                const int xb = (b0 + 0) * (Lsz * Lsz);
                const int sl = hasL ? x[xb + i * Lsz + cl] : 0;
                const int sv = hasV ? x[xb + (i - 1) * Lsz + c] : 0;
                float tot = part[0][0][u] + part[1][0][u] + part[2][0][u] + part[3][0][u] + bc;
                if (hasL) tot += sl ? wih1 : wih0;
                if (hasV) tot += sv ? wiv1 : wiv0;
                const float nv = tot > 0.f ? tot : expm1f(tot);
                h[0][u]     = nv;
                st[0][c][u] = __float2bfloat16(nv);
                l00 = nv * wo0;  l01 = nv * wo1;
            }
            {
                // b = 1
                const int xb = (b0 + 1) * (Lsz * Lsz);
                const int sl = hasL ? x[xb + i * Lsz + cl] : 0;
                const int sv = hasV ? x[xb + (i - 1) * Lsz + c] : 0;
                float tot = part[0][1][u] + part[1][1][u] + part[2][1][u] + part[3][1][u] + bc;
                if (hasL) tot += sl ? wih1 : wih0;
                if (hasV) tot += sv ? wiv1 : wiv0;
                const float nv = tot > 0.f ? tot : expm1f(tot);
                h[1][u]     = nv;
                st[1][c][u] = __float2bfloat16(nv);
                l10 = nv * wo0;  l11 = nv * wo1;
            }

            // wave-level reduction of the 4 logit partials
            for (int off = 32; off; off >>= 1) {
                l00 += __shfl_down(l00, off);
                l01 += __shfl_down(l01, off);
                l10 += __shfl_down(l10, off);
                l11 += __shfl_down(l11, off);
            }
            const int lane = tid & 63;
            const int wid  = tid >> 6;
            if (lane == 0) {
                wred[wid][0][0] = l00;  wred[wid][0][1] = l01;
                wred[wid][1][0] = l10;  wred[wid][1][1] = l11;
            }
            __syncthreads();   // [B]

            if (tid < BPW) {
                float g0 = bo0, g1 = bo1;
                #pragma unroll
                for (int w = 0; w < NT / 64; ++w) {
                    g0 += wred[w][tid][0];
                    g1 += wred[w][tid][1];
                }
                const int sc  = x[(b0 + tid) * (Lsz * Lsz) + i * Lsz + c];
                const float m = fmaxf(g0, g1);
                const float lse = m + logf(expf(g0 - m) + expf(g1 - m));
                logp[tid] += (sc ? g1 : g0) - lse;
            }
            __syncthreads();   // [C]
        }
    }

    if (tid < BPW) {
        float v = logp[tid];
        if (isnan(v)) v = 0.f;
        else if (isinf(v)) v = v > 0.f ? 3.4028235e38f : -3.4028235e38f;
        out[b0 + tid] = v;
    }
}

extern "C" void kernel_launch(void* const* d_in, const int* in_sizes, int n_in,
                              void* d_out, int out_size, void* d_ws, size_t ws_size,
                              hipStream_t stream) {
    const int*   x    = (const int*)  d_in[0];
    const float* Wih  = (const float*)d_in[1];
    const float* Wiv  = (const float*)d_in[2];
    const float* Wch  = (const float*)d_in[3];
    const float* bch  = (const float*)d_in[4];
    const float* Wcv  = (const float*)d_in[5];
    const float* Wout = (const float*)d_in[6];
    const float* bout = (const float*)d_in[7];

    rnn2d_baseline<<<NWG, NT, 0, stream>>>(x, Wih, Wiv, Wch, bch, Wcv, Wout, bout,
                                           (float*)d_out);
}

// Round 2
// 2316.021 us; speedup vs baseline: 1.7409x; 1.7409x over previous
//
#include <hip/hip_runtime.h>
#include <hip/hip_bf16.h>
#include <math.h>

#define Bsz 256
#define Lsz 16
#define Usz 512
#define BPW 2
#define NWG (Bsz / BPW)
#define NT  512

typedef __attribute__((ext_vector_type(8))) short bf16x8;
typedef __attribute__((ext_vector_type(4))) float f32x4;

__device__ __forceinline__ unsigned short f2bf(float f) {
    union { __hip_bfloat16 h; unsigned short s; } u;
    u.h = __float2bfloat16(f);
    return u.s;
}

// LDS state layout: row = c*2+b, XOR-swizzled 16B chunks so MFMA A-frag
// ds_read_b128 across 16 rows is bank-conflict-free.
__device__ __forceinline__ int st_off(int row, int k) {
    return row * Usz + ((k & 504) ^ ((row & 7) << 3)) + (k & 7);
}

// pack Wch fp32 [k][u] -> u32[512][256] (bf16 pairs along u)
__global__ void conv_wch_k(const float* __restrict__ W, unsigned int* __restrict__ out) {
    int j = blockIdx.x * 256 + threadIdx.x;          // 131072 total
    float2 w = *(const float2*)(W + 2 * (size_t)j);
    out[j] = (unsigned)f2bf(w.x) | ((unsigned)f2bf(w.y) << 16);
}

// Wcv fp32 [k][u] -> MFMA B-fragment bf16: tile (kb,ub); lane l holds
// B[k = kb*32 + (l>>4)*8 + j][u = ub*16 + (l&15)], j=0..7, stored contiguous.
__global__ void conv_wcv_k(const float* __restrict__ W, unsigned int* __restrict__ out) {
    int tile = blockIdx.x;            // kb*32+ub, 512 tiles
    int l    = threadIdx.x;           // 64
    int kb = tile >> 5, ub = tile & 31;
    int k0 = kb * 32 + (l >> 4) * 8;
    int u  = ub * 16 + (l & 15);
    unsigned v[4];
    #pragma unroll
    for (int p = 0; p < 4; ++p) {
        unsigned lo = f2bf(W[(size_t)(k0 + 2 * p) * Usz + u]);
        unsigned hi = f2bf(W[(size_t)(k0 + 2 * p + 1) * Usz + u]);
        v[p] = lo | (hi << 16);
    }
    *(uint4*)(out + (size_t)(tile * 64 + l) * 4) = make_uint4(v[0], v[1], v[2], v[3]);
}

__global__ __launch_bounds__(NT) void rnn2d_v2(
    const int*   __restrict__ x,
    const float* __restrict__ Wih,
    const float* __restrict__ Wiv,
    const float* __restrict__ bch,
    const float* __restrict__ Wout,
    const float* __restrict__ bout,
    const unsigned int* __restrict__ wch2,   // bf16-packed [512][256] u32
    const unsigned int* __restrict__ wcvf,   // B-frag swizzled bf16
    float*       __restrict__ out)
{
    __shared__ float          h[2][Usz];                 // 4 KB
    __shared__ unsigned short stm[2 * Lsz * Usz];        // 32 KB, st_off-indexed
    __shared__ float          Vb[2 * Lsz * Usz];         // 64 KB, [row=c*2+b][u]
    __shared__ float          part[4][2][Usz];           // 16 KB
    __shared__ float          wred[8][2][2];
    __shared__ float          logp[2];

    const int tid = threadIdx.x;
    const int b0  = blockIdx.x * BPW;

    if (tid < 2) logp[tid] = 0.f;
    for (int idx = tid; idx < 2 * Lsz * Usz; idx += NT) {
        stm[idx] = 0;
        Vb[idx]  = 0.f;   // V == 0 for row 0 (initial states are zero)
    }

    const int   u    = tid;
    const float wih0 = Wih[u],            wih1 = Wih[Usz + u];
    const float wiv0 = Wiv[u],            wiv1 = Wiv[Usz + u];
    const float bc   = bch[u];
    const float wo0  = Wout[u * 2 + 0],   wo1  = Wout[u * 2 + 1];
    const float bo0  = bout[0],           bo1  = bout[1];

    const int q  = tid & 127;     // u-quad
    const int s  = tid >> 7;      // k-slice
    const int u0 = q * 4;
    const int k0 = s * 128;

    const int wv = tid >> 6;      // wave id (V-pass N-block)
    const int l  = tid & 63;

    for (int i = 0; i < Lsz; ++i) {
        const int dir = (i & 1) ? -1 : 1;

        // ---- per-row V pass: Vb = st_prev_row @ Wcv  (MFMA, off critical path)
        if (i > 0) {
            const int rA = l & 15;
            const int kl = (l >> 4) * 8;
            f32x4 acc[2][4];
            #pragma unroll
            for (int m = 0; m < 2; ++m)
                #pragma unroll
                for (int t = 0; t < 4; ++t) acc[m][t] = (f32x4)(0.f);

            const bf16x8* wf = (const bf16x8*)wcvf;
            for (int kb = 0; kb < 16; ++kb) {
                const int ka = kb * 32 + kl;
                bf16x8 A0 = *(const bf16x8*)&stm[st_off(rA,      ka)];
                bf16x8 A1 = *(const bf16x8*)&stm[st_off(rA + 16, ka)];
                #pragma unroll
                for (int t = 0; t < 4; ++t) {
                    bf16x8 Bf = wf[(size_t)(kb * 32 + wv * 4 + t) * 64 + l];
                    acc[0][t] = __builtin_amdgcn_mfma_f32_16x16x32_bf16(A0, Bf, acc[0][t], 0, 0, 0);
                    acc[1][t] = __builtin_amdgcn_mfma_f32_16x16x32_bf16(A1, Bf, acc[1][t], 0, 0, 0);
                }
            }
            #pragma unroll
            for (int m = 0; m < 2; ++m)
                #pragma unroll
                for (int t = 0; t < 4; ++t)
                    #pragma unroll
                    for (int r = 0; r < 4; ++r) {
                        const int row = m * 16 + (l >> 4) * 4 + r;
                        const int uc  = (wv * 4 + t) * 16 + (l & 15);
                        Vb[row * Usz + uc] = acc[m][t][r];
                    }
        }

        // reset running hidden at row start
        h[0][tid] = 0.f;
        h[1][tid] = 0.f;
        __syncthreads();

        for (int t = 0; t < Lsz; ++t) {
            const int c = (dir == 1) ? t : (Lsz - 1 - t);

            // ---- phase 1: partial h @ Wch over this thread's k-slice (bf16 weights)
            float a00 = 0.f, a01 = 0.f, a02 = 0.f, a03 = 0.f;
            float a10 = 0.f, a11 = 0.f, a12 = 0.f, a13 = 0.f;
            const uint2* wp = (const uint2*)wch2 + (size_t)k0 * 128 + q;
            #pragma unroll 4
            for (int k = k0; k < k0 + 128; ++k) {
                const uint2 w = *wp;  wp += 128;
                const float f0 = __uint_as_float(w.x << 16);
                const float f1 = __uint_as_float(w.x & 0xffff0000u);
                const float f2 = __uint_as_float(w.y << 16);
                const float f3 = __uint_as_float(w.y & 0xffff0000u);
                const float h0 = h[0][k];
                const float h1 = h[1][k];
                a00 += h0 * f0;  a01 += h0 * f1;  a02 += h0 * f2;  a03 += h0 * f3;
                a10 += h1 * f0;  a11 += h1 * f1;  a12 += h1 * f2;  a13 += h1 * f3;
            }
            *(float4*)&part[s][0][u0] = make_float4(a00, a01, a02, a03);
            *(float4*)&part[s][1][u0] = make_float4(a10, a11, a12, a13);
            __syncthreads();   // [A]

            // ---- epilogue: combine + V + inputs, elu, state write, logits
            const int  cl   = c - dir;
            const bool hasL = (t > 0);
            const bool hasV = (i > 0);

            float l00, l01, l10, l11;
            {
                const int xb = (b0 + 0) * (Lsz * Lsz);
                const int sl = hasL ? x[xb + i * Lsz + cl] : 0;
                const int sv = hasV ? x[xb + (i - 1) * Lsz + c] : 0;
                float tot = part[0][0][u] + part[1][0][u] + part[2][0][u] + part[3][0][u]
                          + Vb[(c * 2 + 0) * Usz + u] + bc;
                if (hasL) tot += sl ? wih1 : wih0;
                if (hasV) tot += sv ? wiv1 : wiv0;
                const float nv = tot > 0.f ? tot : expm1f(tot);
                h[0][u] = nv;
                stm[st_off(c * 2 + 0, u)] = f2bf(nv);
                l00 = nv * wo0;  l01 = nv * wo1;
            }
            {
                const int xb = (b0 + 1) * (Lsz * Lsz);
                const int sl = hasL ? x[xb + i * Lsz + cl] : 0;
                const int sv = hasV ? x[xb + (i - 1) * Lsz + c] : 0;
                float tot = part[0][1][u] + part[1][1][u] + part[2][1][u] + part[3][1][u]
                          + Vb[(c * 2 + 1) * Usz + u] + bc;
                if (hasL) tot += sl ? wih1 : wih0;
                if (hasV) tot += sv ? wiv1 : wiv0;
                const float nv = tot > 0.f ? tot : expm1f(tot);
                h[1][u] = nv;
                stm[st_off(c * 2 + 1, u)] = f2bf(nv);
                l10 = nv * wo0;  l11 = nv * wo1;
            }

            for (int off = 32; off; off >>= 1) {
                l00 += __shfl_down(l00, off);
                l01 += __shfl_down(l01, off);
                l10 += __shfl_down(l10, off);
                l11 += __shfl_down(l11, off);
            }
            if (l == 0) {
                wred[wv][0][0] = l00;  wred[wv][0][1] = l01;
                wred[wv][1][0] = l10;  wred[wv][1][1] = l11;
            }
            __syncthreads();   // [B]

            if (tid < 2) {
                float g0 = bo0, g1 = bo1;
                #pragma unroll
                for (int w = 0; w < 8; ++w) {
                    g0 += wred[w][tid][0];
                    g1 += wred[w][tid][1];
                }
                const int   sc = x[(b0 + tid) * (Lsz * Lsz) + i * Lsz + c];
                const float m  = fmaxf(g0, g1);
                const float lse = m + logf(expf(g0 - m) + expf(g1 - m));
                logp[tid] += (sc ? g1 : g0) - lse;
            }
            __syncthreads();   // [C]
        }
    }

    if (tid < 2) {
        float v = logp[tid];
        if (isnan(v)) v = 0.f;
        else if (isinf(v)) v = v > 0.f ? 3.4028235e38f : -3.4028235e38f;
        out[b0 + tid] = v;
    }
}

extern "C" void kernel_launch(void* const* d_in, const int* in_sizes, int n_in,
                              void* d_out, int out_size, void* d_ws, size_t ws_size,
                              hipStream_t stream) {
    const int*   x    = (const int*)  d_in[0];
    const float* Wih  = (const float*)d_in[1];
    const float* Wiv  = (const float*)d_in[2];
    const float* Wch  = (const float*)d_in[3];
    const float* bch  = (const float*)d_in[4];
    const float* Wcv  = (const float*)d_in[5];
    const float* Wout = (const float*)d_in[6];
    const float* bout = (const float*)d_in[7];

    unsigned int* ws_wch = (unsigned int*)d_ws;                            // 512 KB
    unsigned int* ws_wcv = (unsigned int*)((char*)d_ws + 512 * 1024);      // 512 KB

    conv_wch_k<<<512, 256, 0, stream>>>(Wch, ws_wch);
    conv_wcv_k<<<512, 64, 0, stream>>>(Wcv, ws_wcv);
    rnn2d_v2<<<NWG, NT, 0, stream>>>(x, Wih, Wiv, bch, Wout, bout,
                                     ws_wch, ws_wcv, (float*)d_out);
}

// Round 3
// 2229.298 us; speedup vs baseline: 1.8086x; 1.0389x over previous
//
#include <hip/hip_runtime.h>
#include <hip/hip_bf16.h>
#include <math.h>

#define Bsz 256
#define Lsz 16
#define Usz 512
#define BPW 2
#define NWG (Bsz / BPW)     // 128 workgroups, 1 per CU
#define NT  512             // 8 waves

typedef __attribute__((ext_vector_type(8))) short bf16x8;
typedef __attribute__((ext_vector_type(4))) float f32x4;

__device__ __forceinline__ unsigned short f2bf(float f) {
    union { __hip_bfloat16 h; unsigned short s; } u;
    u.h = __float2bfloat16(f);
    return u.s;
}

// state LDS swizzle: row in [0,32), k in [0,512); 16B-chunk XOR keeps
// MFMA A-frag ds_read_b128 across 16 rows conflict-free.
__device__ __forceinline__ int st_off(int row, int k) {
    return row * Usz + ((k & 504) ^ ((row & 7) << 3)) + (k & 7);
}

// Pack fp32 [k][u] (512x512) into MFMA B-fragments, tile id = kb*32+ub:
// lane l holds B[kb*32+(l>>4)*8+j][ub*16+(l&15)], j=0..7, as 4 u32 (bf16 pairs).
// blockIdx < 512 -> Wch, else -> Wcv.
__global__ void conv_frag(const float* __restrict__ Wa, const float* __restrict__ Wb,
                          unsigned int* __restrict__ outa, unsigned int* __restrict__ outb) {
    const int bid  = blockIdx.x;
    const float* W        = (bid < 512) ? Wa : Wb;
    unsigned int* out     = (bid < 512) ? outa : outb;
    const int tile = bid & 511;
    const int l    = threadIdx.x;
    const int kb = tile >> 5, ub = tile & 31;
    const int k0 = kb * 32 + (l >> 4) * 8;
    const int u  = ub * 16 + (l & 15);
    unsigned v[4];
    #pragma unroll
    for (int p = 0; p < 4; ++p) {
        unsigned lo = f2bf(W[(size_t)(k0 + 2 * p) * Usz + u]);
        unsigned hi = f2bf(W[(size_t)(k0 + 2 * p + 1) * Usz + u]);
        v[p] = lo | (hi << 16);
    }
    *(uint4*)(out + (size_t)(tile * 64 + l) * 4) = make_uint4(v[0], v[1], v[2], v[3]);
}

__global__ __launch_bounds__(NT, 2) void rnn2d_v3(
    const int*   __restrict__ x,
    const float* __restrict__ Wih,
    const float* __restrict__ Wiv,
    const float* __restrict__ bch,
    const float* __restrict__ Wout,
    const float* __restrict__ bout,
    const unsigned int* __restrict__ wchf,   // Wch B-frags
    const unsigned int* __restrict__ wcvf,   // Wcv B-frags
    float*       __restrict__ out)
{
    __shared__ __attribute__((aligned(16))) unsigned short stm[32 * Usz];   // 32 KB states
    __shared__ float Vb[32 * Usz];                                          // 64 KB V=st@Wcv
    __shared__ __attribute__((aligned(16))) unsigned short hb[2][2][Usz];   // 4 KB h dbuf (bf16)
    __shared__ __attribute__((aligned(16))) unsigned short zc[8];           // zero A-chunk
    __shared__ float wihA[2][Usz], wivA[2][Usz], bcA[Usz], woA[Usz][2];     // 14 KB tables
    __shared__ float wred[2][8][2][2];
    __shared__ float logp[2];

    const int tid = threadIdx.x;
    const int b0  = blockIdx.x * BPW;
    const int w   = tid >> 6;     // wave id: owns u-slice [w*64, w*64+64)
    const int l   = tid & 63;
    const int r   = l & 15;
    const int hi4 = l >> 4;

    // ---- one-time init ----
    if (tid < 2) logp[tid] = 0.f;
    if (tid < 8) zc[tid] = 0;
    for (int idx = tid; idx < 32 * Usz; idx += NT) Vb[idx] = 0.f;   // row 0 has no V
    wihA[0][tid] = Wih[tid];  wihA[1][tid] = Wih[Usz + tid];
    wivA[0][tid] = Wiv[tid];  wivA[1][tid] = Wiv[Usz + tid];
    bcA[tid] = bch[tid];
    woA[tid][0] = Wout[2 * tid];  woA[tid][1] = Wout[2 * tid + 1];
    const float bo0 = bout[0], bo1 = bout[1];

    // ---- register-resident Wch: tiles t=0,1 of this wave's 4 n-tiles ----
    const bf16x8* __restrict__ WF = (const bf16x8*)wchf;
    const bf16x8* __restrict__ VF = (const bf16x8*)wcvf;
    bf16x8 wreg[32];
    #pragma unroll
    for (int kb = 0; kb < 16; ++kb) {
        wreg[2 * kb]     = WF[(kb * 32 + w * 4 + 0) * 64 + l];
        wreg[2 * kb + 1] = WF[(kb * 32 + w * 4 + 1) * 64 + l];
    }

    int p = 0;
    for (int i = 0; i < Lsz; ++i) {
        const int dir = (i & 1) ? -1 : 1;

        // ---- per-row V-pass: Vb = st(prev row) @ Wcv (MFMA, off critical path)
        if (i > 0) {
            f32x4 vacc[2][4];
            #pragma unroll
            for (int m = 0; m < 2; ++m)
                #pragma unroll
                for (int t4 = 0; t4 < 4; ++t4) vacc[m][t4] = (f32x4)(0.f);
            const int kl = hi4 * 8;
            for (int kb = 0; kb < 16; ++kb) {
                const int ka = kb * 32 + kl;
                bf16x8 A0 = *(const bf16x8*)&stm[st_off(r,      ka)];
                bf16x8 A1 = *(const bf16x8*)&stm[st_off(r + 16, ka)];
                #pragma unroll
                for (int t4 = 0; t4 < 4; ++t4) {
                    bf16x8 Bf = VF[(size_t)(kb * 32 + w * 4 + t4) * 64 + l];
                    vacc[0][t4] = __builtin_amdgcn_mfma_f32_16x16x32_bf16(A0, Bf, vacc[0][t4], 0, 0, 0);
                    vacc[1][t4] = __builtin_amdgcn_mfma_f32_16x16x32_bf16(A1, Bf, vacc[1][t4], 0, 0, 0);
                }
            }
            #pragma unroll
            for (int m = 0; m < 2; ++m)
                #pragma unroll
                for (int t4 = 0; t4 < 4; ++t4)
                    #pragma unroll
                    for (int q = 0; q < 4; ++q) {
                        const int row = m * 16 + hi4 * 4 + q;
                        const int uc  = (w * 4 + t4) * 16 + r;
                        Vb[row * Usz + uc] = vacc[m][t4][q];
                    }
        }

        // zero both h buffers (h resets each row)
        for (int idx = tid; idx < 2 * 2 * Usz; idx += NT)
            ((unsigned short*)hb)[idx] = 0;
        __syncthreads();

        for (int t = 0; t < Lsz; ++t) {
            const int c = (dir == 1) ? t : (Lsz - 1 - t);

            // ---- MFMA: newh = h @ Wch (batch = A rows 0,1) ----
            f32x4 acc0 = (f32x4)(0.f), acc1 = (f32x4)(0.f),
                  acc2 = (f32x4)(0.f), acc3 = (f32x4)(0.f);
            bf16x8 sbuf[16];
            #pragma unroll
            for (int kb = 0; kb < 16; ++kb)
                sbuf[kb] = WF[(kb * 32 + w * 4 + 2) * 64 + l];
            #pragma unroll
            for (int kb = 0; kb < 16; ++kb) {
                const bf16x8 Af = (r < 2)
                    ? *(const bf16x8*)&hb[p][r][((kb * 4 + hi4) ^ r) << 3]
                    : *(const bf16x8*)zc;
                acc0 = __builtin_amdgcn_mfma_f32_16x16x32_bf16(Af, wreg[2 * kb],     acc0, 0, 0, 0);
                acc1 = __builtin_amdgcn_mfma_f32_16x16x32_bf16(Af, wreg[2 * kb + 1], acc1, 0, 0, 0);
                acc2 = __builtin_amdgcn_mfma_f32_16x16x32_bf16(Af, sbuf[kb],         acc2, 0, 0, 0);
            }
            #pragma unroll
            for (int kb = 0; kb < 16; ++kb)
                sbuf[kb] = WF[(kb * 32 + w * 4 + 3) * 64 + l];
            #pragma unroll
            for (int kb = 0; kb < 16; ++kb) {
                const bf16x8 Af = (r < 2)
                    ? *(const bf16x8*)&hb[p][r][((kb * 4 + hi4) ^ r) << 3]
                    : *(const bf16x8*)zc;
                acc3 = __builtin_amdgcn_mfma_f32_16x16x32_bf16(Af, sbuf[kb], acc3, 0, 0, 0);
            }

            // ---- epilogue (C rows 0,1 live in lanes 0-15, regs 0,1) ----
            const int  cl   = c - dir;
            const bool hasL = (t > 0);
            const bool hasV = (i > 0);
            if (l < 16) {
                const int sl0 = hasL ? x[(b0 + 0) * 256 + i * 16 + cl]      : 0;
                const int sv0 = hasV ? x[(b0 + 0) * 256 + (i - 1) * 16 + c] : 0;
                const int sl1 = hasL ? x[(b0 + 1) * 256 + i * 16 + cl]      : 0;
                const int sv1 = hasV ? x[(b0 + 1) * 256 + (i - 1) * 16 + c] : 0;
                float lp00 = 0.f, lp01 = 0.f, lp10 = 0.f, lp11 = 0.f;

                #define EPI(ACC, TQ) { \
                    const int u = w * 64 + (TQ) * 16 + l; \
                    float v0 = (ACC)[0] + Vb[(c * 2 + 0) * Usz + u] + bcA[u]; \
                    float v1 = (ACC)[1] + Vb[(c * 2 + 1) * Usz + u] + bcA[u]; \
                    if (hasL) { v0 += wihA[sl0][u]; v1 += wihA[sl1][u]; } \
                    if (hasV) { v0 += wivA[sv0][u]; v1 += wivA[sv1][u]; } \
                    v0 = v0 > 0.f ? v0 : expm1f(v0); \
                    v1 = v1 > 0.f ? v1 : expm1f(v1); \
                    hb[p ^ 1][0][(((u >> 3) ^ 0) << 3) | (u & 7)] = f2bf(v0); \
                    hb[p ^ 1][1][(((u >> 3) ^ 1) << 3) | (u & 7)] = f2bf(v1); \
                    stm[st_off(c * 2 + 0, u)] = f2bf(v0); \
                    stm[st_off(c * 2 + 1, u)] = f2bf(v1); \
                    lp00 += v0 * woA[u][0];  lp01 += v0 * woA[u][1]; \
                    lp10 += v1 * woA[u][0];  lp11 += v1 * woA[u][1]; }

                EPI(acc0, 0)
                EPI(acc1, 1)
                EPI(acc2, 2)
                EPI(acc3, 3)
                #undef EPI

                #pragma unroll
                for (int off = 8; off; off >>= 1) {
                    lp00 += __shfl_down(lp00, off);
                    lp01 += __shfl_down(lp01, off);
                    lp10 += __shfl_down(lp10, off);
                    lp11 += __shfl_down(lp11, off);
                }
                if (l == 0) {
                    wred[t & 1][w][0][0] = lp00;  wred[t & 1][w][0][1] = lp01;
                    wred[t & 1][w][1][0] = lp10;  wred[t & 1][w][1][1] = lp11;
                }
            }
            __syncthreads();

            if (tid < 2) {
                float g0 = bo0, g1 = bo1;
                #pragma unroll
                for (int ww = 0; ww < 8; ++ww) {
                    g0 += wred[t & 1][ww][tid][0];
                    g1 += wred[t & 1][ww][tid][1];
                }
                const int   sc = x[(b0 + tid) * 256 + i * 16 + c];
                const float m  = fmaxf(g0, g1);
                const float lse = m + logf(expf(g0 - m) + expf(g1 - m));
                logp[tid] += (sc ? g1 : g0) - lse;
            }
            p ^= 1;
        }
    }

    if (tid < 2) {
        float v = logp[tid];
        if (isnan(v)) v = 0.f;
        else if (isinf(v)) v = v > 0.f ? 3.4028235e38f : -3.4028235e38f;
        out[b0 + tid] = v;
    }
}

extern "C" void kernel_launch(void* const* d_in, const int* in_sizes, int n_in,
                              void* d_out, int out_size, void* d_ws, size_t ws_size,
                              hipStream_t stream) {
    const int*   x    = (const int*)  d_in[0];
    const float* Wih  = (const float*)d_in[1];
    const float* Wiv  = (const float*)d_in[2];
    const float* Wch  = (const float*)d_in[3];
    const float* bch  = (const float*)d_in[4];
    const float* Wcv  = (const float*)d_in[5];
    const float* Wout = (const float*)d_in[6];
    const float* bout = (const float*)d_in[7];

    unsigned int* ws_wch = (unsigned int*)d_ws;                          // 512 KB
    unsigned int* ws_wcv = (unsigned int*)((char*)d_ws + 512 * 1024);    // 512 KB

    conv_frag<<<1024, 64, 0, stream>>>(Wch, Wcv, ws_wch, ws_wcv);
    rnn2d_v3<<<NWG, NT, 0, stream>>>(x, Wih, Wiv, bch, Wout, bout,
                                     ws_wch, ws_wcv, (float*)d_out);
}